// Round 10
// baseline (433.088 us; speedup 1.0000x reference)
//
#include <hip/hip_runtime.h>

// 10-qubit batched statevector simulator.
// One wave (64 lanes) per sample; persistent grid: 2048 blocks x 4 waves,
// each wave handling 4 samples (B = 32768). Setup once per block.
// Amp index bits: 0..5 = lane bits, 6..8 = k-index of v2f arrays,
// 9 = element (x/y) of each v2f. Qubit q (MSB-first) is amp bit p = 9-q.
//
// Round-10 vs round-9 (spill persisted: 810 MB FETCH at 40 VGPR under cap 42):
//  - HW model update: launch_bounds VGPR cap = 256/min_waves (pool ~256/SIMD
//    for wave64). Round-9 body truly needed ~50 -> allocator spilled to fit 42.
//  - Fix the PEAK, not the cap: on-demand trig in the init fold (each qubit's
//    cos/sin computed where consumed; max ~4 trig regs live vs 20).
//  - scalar input loads (round-6 style, no staging array); keep persistent
//    grid and __launch_bounds__(256,6).

namespace {

constexpr int NQB = 10;
constexpr int SPW = 4;     // samples per wave (grid-stride)

typedef float v2f __attribute__((ext_vector_type(2)));

template<int CTRL>
__device__ __forceinline__ float dppf(float x) {
  return __uint_as_float((unsigned)__builtin_amdgcn_update_dpp(
      0, (int)__float_as_uint(x), CTRL, 0xF, 0xF, true));
}

// Partner value x[lane ^ (1<<P)].
// P=0,1,3: single DPP. P=2: ds_swizzle XOR4. P=4: ds_swizzle XOR16.
// P=5: ds_bpermute (addr bpa = (lane^32)<<2).
template<int P>
__device__ __forceinline__ float xorf(float x, int bpa) {
  if constexpr (P == 0) {
    return dppf<0xB1>(x);                       // quad_perm [1,0,3,2] = XOR1
  } else if constexpr (P == 1) {
    return dppf<0x4E>(x);                       // quad_perm [2,3,0,1] = XOR2
  } else if constexpr (P == 2) {
    return __uint_as_float((unsigned)__builtin_amdgcn_ds_swizzle(
        (int)__float_as_uint(x), 0x101F));      // bitmode xor=4
  } else if constexpr (P == 3) {
    return dppf<0x128>(x);                      // row_ror:8 == XOR8 within row16
  } else if constexpr (P == 4) {
    return __uint_as_float((unsigned)__builtin_amdgcn_ds_swizzle(
        (int)__float_as_uint(x), 0x401F));      // bitmode xor=16
  } else {
    return __uint_as_float((unsigned)__builtin_amdgcn_ds_bpermute(
        bpa, (int)__float_as_uint(x)));
  }
}

template<int P>
__device__ __forceinline__ v2f partner2(v2f v, int bpa) {
  v2f r;
  r.x = xorf<P>(v.x, bpa);
  r.y = xorf<P>(v.y, bpa);
  return r;
}

__device__ __forceinline__ float fsin_rev(float rev) {
#if __has_builtin(__builtin_amdgcn_sinf)
  return __builtin_amdgcn_sinf(rev);
#else
  return __sinf(rev * 6.2831853071795864769f);
#endif
}
__device__ __forceinline__ float fcos_rev(float rev) {
#if __has_builtin(__builtin_amdgcn_cosf)
  return __builtin_amdgcn_cosf(rev);
#else
  return __cosf(rev * 6.2831853071795864769f);
#endif
}

__device__ __forceinline__ float clamp01(float x) {
#if __has_builtin(__builtin_amdgcn_fmed3f)
  return __builtin_amdgcn_fmed3f(x, 0.0f, 1.0f);
#else
  return fminf(fmaxf(x, 0.0f), 1.0f);
#endif
}

__device__ __forceinline__ void cmul(float& r, float& i, float br, float bi) {
  const float tr = r * br - i * bi;
  i = r * bi + i * br;
  r = tr;
}

// ---- diagonal layer: S[k] *= (zr + i zi) * RA[k][axis] ----
__device__ __forceinline__ void apply_diag(v2f (&Sr)[8], v2f (&Si)[8],
                                           float zr, float zi, const float (*tab)[4]) {
#pragma unroll
  for (int k = 0; k < 8; ++k) {
    const float4 t4 = *(const float4*)&tab[k][0];
    const v2f Rr = {t4.x, t4.y}, Ri = {t4.z, t4.w};
    const v2f tr = zr*Sr[k] - zi*Si[k];
    const v2f ti = zi*Sr[k] + zr*Si[k];
    Sr[k] = tr*Rr - ti*Ri;
    Si[k] = tr*Ri + ti*Rr;
  }
}

// ---- real RY gates (c = cos(th/2), s = sin(th/2)) ----

__device__ __forceinline__ void ry_axis(v2f (&Sr)[8], v2f (&Si)[8], float c, float s) {
  const v2f sv = {-s, s};
#pragma unroll
  for (int k = 0; k < 8; ++k) {
    const v2f ar = Sr[k], ai = Si[k];
    Sr[k] = c*ar + sv*ar.yx;
    Si[k] = c*ai + sv*ai.yx;
  }
}

template<int J>
__device__ __forceinline__ void ry_reg(v2f (&Sr)[8], v2f (&Si)[8], float c, float s) {
#pragma unroll
  for (int k0 = 0; k0 < 8; ++k0) {
    if (k0 & J) continue;
    const int k1 = k0 | J;
    const v2f a0r=Sr[k0], a0i=Si[k0], a1r=Sr[k1], a1i=Si[k1];
    Sr[k0] = c*a0r - s*a1r;  Si[k0] = c*a0i - s*a1i;
    Sr[k1] = s*a0r + c*a1r;  Si[k1] = s*a0i + c*a1i;
  }
}

template<int P>
__device__ __forceinline__ void ry_lane(v2f (&Sr)[8], v2f (&Si)[8], float c, float s,
                                        int lane, int bpa) {
  const float ss = ((lane >> P) & 1) ? s : -s;
#pragma unroll
  for (int k = 0; k < 8; ++k) {
    const v2f pr = partner2<P>(Sr[k], bpa), pi = partner2<P>(Si[k], bpa);
    Sr[k] = c*Sr[k] + ss*pr;
    Si[k] = c*Si[k] + ss*pi;
  }
}

// ---- CRY gates (real c = cos(th/2), s = sin(th/2); control==1 applies RY) ----

template<int CB, int J>
__device__ __forceinline__ void cry_reg_reg(v2f (&Sr)[8], v2f (&Si)[8], float c, float s) {
#pragma unroll
  for (int k0 = 0; k0 < 8; ++k0) {
    if ((k0 & J) || !(k0 & CB)) continue;
    const int k1 = k0 | J;
    const v2f a0r=Sr[k0], a0i=Si[k0], a1r=Sr[k1], a1i=Si[k1];
    Sr[k0] = c*a0r - s*a1r;  Si[k0] = c*a0i - s*a1i;
    Sr[k1] = s*a0r + c*a1r;  Si[k1] = s*a0i + c*a1i;
  }
}

// control on packing axis (bit 9), target k-bit 4 (amp bit 8)
__device__ __forceinline__ void cry_axisctrl(v2f (&Sr)[8], v2f (&Si)[8], float c, float s) {
  const v2f cv = {1.0f, c}, sv = {0.0f, s};
#pragma unroll
  for (int k0 = 0; k0 < 4; ++k0) {
    const int k1 = k0 + 4;
    const v2f a0r=Sr[k0], a0i=Si[k0], a1r=Sr[k1], a1i=Si[k1];
    Sr[k0] = cv*a0r - sv*a1r;  Si[k0] = cv*a0i - sv*a1i;
    Sr[k1] = sv*a0r + cv*a1r;  Si[k1] = sv*a0i + cv*a1i;
  }
}

// control k-bit 1 (amp bit 6), target lane bit 5
__device__ __forceinline__ void cry_k0ctrl_lane5(v2f (&Sr)[8], v2f (&Si)[8],
                                                 float c, float s, int lane, int bpa) {
  const float ss = ((lane >> 5) & 1) ? s : -s;
#pragma unroll
  for (int k = 1; k < 8; k += 2) {
    const v2f pr = partner2<5>(Sr[k], bpa), pi = partner2<5>(Si[k], bpa);
    Sr[k] = c*Sr[k] + ss*pr;
    Si[k] = c*Si[k] + ss*pi;
  }
}

template<int PC, int PT>
__device__ __forceinline__ void cry_lane_lane(v2f (&Sr)[8], v2f (&Si)[8],
                                              float c, float s, int lane, int bpa) {
  const bool ctrl = (lane >> PC) & 1;
  const float ce = ctrl ? c : 1.0f;
  const float se = ctrl ? s : 0.0f;
  const float ss = ((lane >> PT) & 1) ? se : -se;
#pragma unroll
  for (int k = 0; k < 8; ++k) {
    const v2f pr = partner2<PT>(Sr[k], bpa), pi = partner2<PT>(Si[k], bpa);
    Sr[k] = ce*Sr[k] + ss*pr;
    Si[k] = ce*Si[k] + ss*pi;
  }
}

// control lane bit 0, target packing axis (bit 9)
__device__ __forceinline__ void cry_lanectrl_axis(v2f (&Sr)[8], v2f (&Si)[8],
                                                  float c, float s, int lane) {
  const bool ctrl = lane & 1;
  const float ce = ctrl ? c : 1.0f;
  const float se = ctrl ? s : 0.0f;
  const v2f sv = {-se, se};
#pragma unroll
  for (int k = 0; k < 8; ++k) {
    const v2f ar = Sr[k], ai = Si[k];
    Sr[k] = ce*ar + sv*ar.yx;
    Si[k] = ce*ai + sv*ai.yx;
  }
}

} // namespace

__global__ __launch_bounds__(256, 6)
void qlayer_kernel(const float* __restrict__ inp,   // (B, 10)
                   const float* __restrict__ wt,    // (80,)
                   float* __restrict__ out,         // (B, 10)
                   int B)
{
  __shared__ float gm[10][8];                    // layer-0 Rot matrices
  __shared__ float gc[20][2];                    // CRY cos/sin, both layers
  __shared__ float grot1[10][2];                 // layer-1 RY cos/sin
  __shared__ __align__(16) float gdphi[8][4];    // layer-1 D_phi reg/axis phases
  __shared__ __align__(16) float gdome[8][4];    // layer-1 D_omega reg/axis phases
  __shared__ float gzlane[2][64][2];             // per-lane diag phase (c,s): [0]=phi,[1]=omega

  const int tid = threadIdx.x;

  // ---- setup (once per block; disjoint thread ranges in parallel) ----
  if (tid < 10) {
    // layer-0 Rot(phi, theta, omega) = RZ(omega) RY(theta) RZ(phi)
    const int w = 3 * tid;
    const float phi = wt[w], th = wt[w + 1], om = wt[w + 2];
    float s, c, sa, ca, sb, cb;
    __sincosf(0.5f * th, &s, &c);
    __sincosf(0.5f * (phi + om), &sa, &ca);
    __sincosf(0.5f * (phi - om), &sb, &cb);
    gm[tid][0] =  c * ca;  gm[tid][1] = -c * sa;   // u00
    gm[tid][2] = -s * cb;  gm[tid][3] = -s * sb;   // u01
    gm[tid][4] =  s * cb;  gm[tid][5] = -s * sb;   // u10
    gm[tid][6] =  c * ca;  gm[tid][7] =  c * sa;   // u11
  } else if (tid < 30) {
    const int g = tid - 10;
    const int layer = g / 10, e = g - 10 * layer;
    const int w = layer * 40 + 30 + e;
    float s, c;
    __sincosf(0.5f * wt[w], &s, &c);
    gc[g][0] = c;
    gc[g][1] = s;
  } else if (tid < 40) {
    const int q = tid - 30;
    float s, c;
    __sincosf(0.5f * wt[41 + 3 * q], &s, &c);    // layer-1 theta_q
    grot1[q][0] = c;
    grot1[q][1] = s;
  } else if (tid < 72) {
    // layer-1 diagonal reg/axis tables: k bit0<->q3, bit1<->q2, bit2<->q1, axis<->q0
    const int t = tid - 40;
    const int dia = t >> 4;            // 0: phi (wt[40+3q]), 1: omega (wt[42+3q])
    const int u = t & 15;
    const int k = u & 7, ax = u >> 3;
    const int wb = dia ? 42 : 40;
    float ang = 0.0f;
    if (k & 1) ang += wt[wb + 9];
    if (k & 2) ang += wt[wb + 6];
    if (k & 4) ang += wt[wb + 3];
    if (ax)    ang += wt[wb + 0];
    float s, c;
    __sincosf(ang, &s, &c);
    float* gd = dia ? &gdome[0][0] : &gdphi[0][0];
    gd[k * 4 + ax]     = c;
    gd[k * 4 + 2 + ax] = s;
  } else if (tid >= 128) {
    // per-lane diag phase (lane bit p <-> qubit 9-p): angle sum over set bits
    const int d = (tid - 128) >> 6, ln = tid & 63;
    const int wb = d ? 42 : 40;
    float ang = 0.0f;
    if (ln & 1)  ang += wt[wb + 27];
    if (ln & 2)  ang += wt[wb + 24];
    if (ln & 4)  ang += wt[wb + 21];
    if (ln & 8)  ang += wt[wb + 18];
    if (ln & 16) ang += wt[wb + 15];
    if (ln & 32) ang += wt[wb + 12];
    float s, c;
    __sincosf(ang, &s, &c);
    gzlane[d][ln][0] = c;
    gzlane[d][ln][1] = s;
  }
  __syncthreads();

  const int lane = tid & 63;
  const int bpa = (lane ^ 32) << 2;              // ds_bpermute byte address
  const int gw = blockIdx.x * 4 + (tid >> 6);    // global wave id, 0..8191
  const int wstride = gridDim.x * 4;             // 8192

#pragma unroll 1
  for (int j = 0; j < SPW; ++j) {
    const int sample = gw + j * wstride;
    if (sample >= B) break;
    const float* xin = inp + sample * NQB;

    // ---- init: product state through (embedding RY) + (layer-0 Rot).
    // On-demand trig: each qubit's (cos,sin) computed where consumed, so at
    // most ~4 trig values are live at once (register-peak fix, round-10). ----

    // lane factor L = prod_{p=0..5} u_p[lane bit p],  u_p = Rot_{9-p} (fc,fs)^T
    float Lr, Li;
#pragma unroll
    for (int p = 0; p < 6; ++p) {
      const float r = 0.25f * clamp01(xin[9 - p]);   // (pi/2*x) in revolutions
      const float fs = fsin_rev(r), fc = fcos_rev(r);
      const float* m = &gm[9 - p][0];
      const bool b = (lane >> p) & 1;
      const float m0 = b ? m[4] : m[0], m1 = b ? m[5] : m[1];
      const float m2 = b ? m[6] : m[2], m3 = b ? m[7] : m[3];
      const float ur = m0 * fc + m2 * fs;
      const float ui = m1 * fc + m3 * fs;
      if (p == 0) { Lr = ur; Li = ui; }
      else        cmul(Lr, Li, ur, ui);
    }

    // register-factor tree A[k] = L * u6[k&1] * u7[(k>>1)&1] * u8[(k>>2)&1]
    float Ar[8], Ai[8];
    {
      const float r = 0.25f * clamp01(xin[3]);       // amp bit 6 -> q=3
      const float fs = fsin_rev(r), fc = fcos_rev(r);
      const float* m = &gm[3][0];
      const float u0r = m[0]*fc + m[2]*fs, u0i = m[1]*fc + m[3]*fs;
      const float u1r = m[4]*fc + m[6]*fs, u1i = m[5]*fc + m[7]*fs;
      Ar[0] = Lr*u0r - Li*u0i;  Ai[0] = Lr*u0i + Li*u0r;
      Ar[1] = Lr*u1r - Li*u1i;  Ai[1] = Lr*u1i + Li*u1r;
    }
    {
      const float r = 0.25f * clamp01(xin[2]);       // amp bit 7 -> q=2
      const float fs = fsin_rev(r), fc = fcos_rev(r);
      const float* m = &gm[2][0];
      const float u0r = m[0]*fc + m[2]*fs, u0i = m[1]*fc + m[3]*fs;
      const float u1r = m[4]*fc + m[6]*fs, u1i = m[5]*fc + m[7]*fs;
#pragma unroll
      for (int k = 0; k < 2; ++k) {
        Ar[k+2] = Ar[k]*u1r - Ai[k]*u1i;  Ai[k+2] = Ar[k]*u1i + Ai[k]*u1r;
        cmul(Ar[k], Ai[k], u0r, u0i);
      }
    }
    {
      const float r = 0.25f * clamp01(xin[1]);       // amp bit 8 -> q=1
      const float fs = fsin_rev(r), fc = fcos_rev(r);
      const float* m = &gm[1][0];
      const float u0r = m[0]*fc + m[2]*fs, u0i = m[1]*fc + m[3]*fs;
      const float u1r = m[4]*fc + m[6]*fs, u1i = m[5]*fc + m[7]*fs;
#pragma unroll
      for (int k = 0; k < 4; ++k) {
        Ar[k+4] = Ar[k]*u1r - Ai[k]*u1i;  Ai[k+4] = Ar[k]*u1i + Ai[k]*u1r;
        cmul(Ar[k], Ai[k], u0r, u0i);
      }
    }

    v2f Sr[8], Si[8];
    {
      const float r = 0.25f * clamp01(xin[0]);       // amp bit 9 (axis) -> q=0
      const float fs = fsin_rev(r), fc = fcos_rev(r);
      const float* m = &gm[0][0];
      const v2f u9r = {m[0]*fc + m[2]*fs, m[4]*fc + m[6]*fs};
      const v2f u9i = {m[1]*fc + m[3]*fs, m[5]*fc + m[7]*fs};
#pragma unroll
      for (int k = 0; k < 8; ++k) {
        Sr[k] = Ar[k]*u9r - Ai[k]*u9i;
        Si[k] = Ar[k]*u9i + Ai[k]*u9r;
      }
    }

    // ---- layer 0: CRY ring (Rot folded into init) ----
    {
      const float (*cc)[2] = &gc[0];
      cry_axisctrl        (Sr, Si, cc[0][0], cc[0][1]);              // (p9,p8)
      cry_reg_reg<4, 2>   (Sr, Si, cc[1][0], cc[1][1]);              // (p8,p7)
      cry_reg_reg<2, 1>   (Sr, Si, cc[2][0], cc[2][1]);              // (p7,p6)
      cry_k0ctrl_lane5    (Sr, Si, cc[3][0], cc[3][1], lane, bpa);   // (p6,p5)
      cry_lane_lane<5, 4> (Sr, Si, cc[4][0], cc[4][1], lane, bpa);
      cry_lane_lane<4, 3> (Sr, Si, cc[5][0], cc[5][1], lane, bpa);
      cry_lane_lane<3, 2> (Sr, Si, cc[6][0], cc[6][1], lane, bpa);
      cry_lane_lane<2, 1> (Sr, Si, cc[7][0], cc[7][1], lane, bpa);
      cry_lane_lane<1, 0> (Sr, Si, cc[8][0], cc[8][1], lane, bpa);
      cry_lanectrl_axis   (Sr, Si, cc[9][0], cc[9][1], lane);        // (p0,p9)
    }

    // ---- layer 1: D_phi -> real RY layer -> D_omega -> CRY ring ----
    {
      const float2 zp = *(const float2*)&gzlane[0][lane][0];
      apply_diag(Sr, Si, zp.x, zp.y, gdphi);
      ry_axis   (Sr, Si, grot1[0][0], grot1[0][1]);          // q=0, axis
      ry_reg<4> (Sr, Si, grot1[1][0], grot1[1][1]);          // q=1, amp bit 8
      ry_reg<2> (Sr, Si, grot1[2][0], grot1[2][1]);          // q=2, amp bit 7
      ry_reg<1> (Sr, Si, grot1[3][0], grot1[3][1]);          // q=3, amp bit 6
      ry_lane<5>(Sr, Si, grot1[4][0], grot1[4][1], lane, bpa);
      ry_lane<4>(Sr, Si, grot1[5][0], grot1[5][1], lane, bpa);
      ry_lane<3>(Sr, Si, grot1[6][0], grot1[6][1], lane, bpa);
      ry_lane<2>(Sr, Si, grot1[7][0], grot1[7][1], lane, bpa);
      ry_lane<1>(Sr, Si, grot1[8][0], grot1[8][1], lane, bpa);
      ry_lane<0>(Sr, Si, grot1[9][0], grot1[9][1], lane, bpa);
      const float2 zo = *(const float2*)&gzlane[1][lane][0];
      apply_diag(Sr, Si, zo.x, zo.y, gdome);

      const float (*cc)[2] = &gc[10];
      cry_axisctrl        (Sr, Si, cc[0][0], cc[0][1]);
      cry_reg_reg<4, 2>   (Sr, Si, cc[1][0], cc[1][1]);
      cry_reg_reg<2, 1>   (Sr, Si, cc[2][0], cc[2][1]);
      cry_k0ctrl_lane5    (Sr, Si, cc[3][0], cc[3][1], lane, bpa);
      cry_lane_lane<5, 4> (Sr, Si, cc[4][0], cc[4][1], lane, bpa);
      cry_lane_lane<4, 3> (Sr, Si, cc[5][0], cc[5][1], lane, bpa);
      cry_lane_lane<3, 2> (Sr, Si, cc[6][0], cc[6][1], lane, bpa);
      cry_lane_lane<2, 1> (Sr, Si, cc[7][0], cc[7][1], lane, bpa);
      cry_lane_lane<1, 0> (Sr, Si, cc[8][0], cc[8][1], lane, bpa);
      cry_lanectrl_axis   (Sr, Si, cc[9][0], cc[9][1], lane);
    }

    // ---- probabilities and PauliZ expvals ----
    v2f P[8];
#pragma unroll
    for (int k = 0; k < 8; ++k) P[k] = Sr[k]*Sr[k] + Si[k]*Si[k];

    const v2f q01 = P[0]+P[1], q23 = P[2]+P[3], q45 = P[4]+P[5], q67 = P[6]+P[7];
    const v2f h1 = q01+q23, h2 = q45+q67;
    const v2f t2 = h1 + h2;                           // per-lane total
    const v2f e8v = h1 - h2;                          // sign on amp bit 8
    const v2f e7v = (q01 - q23) + (q45 - q67);        // sign on amp bit 7
    const v2f d01 = P[0]-P[1], d23 = P[2]-P[3], d45 = P[4]-P[5], d67 = P[6]-P[7];
    const v2f e6v = (d01 + d23) + (d45 + d67);        // sign on amp bit 6

    const float tot = t2.x + t2.y;
    const float o6 = e6v.x + e6v.y;
    const float o7 = e7v.x + e7v.y;
    const float o8 = e8v.x + e8v.y;
    const float o9 = t2.x - t2.y;

    float sgn[6];
#pragma unroll
    for (int p = 0; p < 6; ++p) sgn[p] = ((lane >> p) & 1) ? -1.0f : 1.0f;

    float E[6];
    float t = tot;
#define QSTEP(P)                                             \
    {                                                        \
      const float pt = xorf<P>(t, bpa);                      \
      E[P] = sgn[P] * (t - pt);                              \
      t += pt;                                               \
      _Pragma("unroll")                                      \
      for (int jj = 0; jj < P; ++jj) E[jj] += xorf<P>(E[jj], bpa); \
    }
    QSTEP(0) QSTEP(1) QSTEP(2) QSTEP(3) QSTEP(4) QSTEP(5)
#undef QSTEP

    v2f q1; q1.x = o6; q1.y = o7;
    v2f q2; q2.x = o8; q2.y = o9;
#define RSTEP(P)                   \
    q1 += partner2<P>(q1, bpa);    \
    q2 += partner2<P>(q2, bpa);
    RSTEP(0) RSTEP(1) RSTEP(2) RSTEP(3) RSTEP(4) RSTEP(5)
#undef RSTEP

    // out[sample][q], q = 9 - p:  q=0..3 <- bits 9,8,7,6 ; q=4..9 <- E[5..0]
    if (lane < 10) {
      float v = q2.y;                  // q=0: bit 9
      v = (lane == 1) ? q2.x : v;      // bit 8
      v = (lane == 2) ? q1.y : v;      // bit 7
      v = (lane == 3) ? q1.x : v;      // bit 6
      v = (lane == 4) ? E[5] : v;
      v = (lane == 5) ? E[4] : v;
      v = (lane == 6) ? E[3] : v;
      v = (lane == 7) ? E[2] : v;
      v = (lane == 8) ? E[1] : v;
      v = (lane == 9) ? E[0] : v;
      out[sample * NQB + lane] = v;
    }
  }
}

extern "C" void kernel_launch(void* const* d_in, const int* in_sizes, int n_in,
                              void* d_out, int out_size, void* d_ws, size_t ws_size,
                              hipStream_t stream) {
  const float* inp = (const float*)d_in[0];
  const float* wt  = (const float*)d_in[1];
  float* out = (float*)d_out;
  const int B = in_sizes[0] / NQB;              // 32768
  const int total_waves = (B + SPW - 1) / SPW;  // 8192
  const int nblocks = (total_waves + 3) / 4;    // 2048
  hipLaunchKernelGGL(qlayer_kernel, dim3(nblocks), dim3(256), 0, stream,
                     inp, wt, out, B);
}

// Round 12
// 111.323 us; speedup vs baseline: 3.8904x; 3.8904x over previous
//
#include <hip/hip_runtime.h>

// 10-qubit batched statevector simulator -- packed-f16, 2 samples per wave.
// One wave (64 lanes) handles samples {gw, gw + B/2} simultaneously:
// state = h2 Hr[16], Hi[16]; each 32-bit VGPR holds {sampleA, sampleB} f16.
// Amp index bits: 0..5 = lane bits, 6..9 = register index k (bit6->k0 ... bit9->k3).
// Qubit q (MSB-first) is amp bit p = 9-q.
// Every pk-f16 arithmetic op and every 32-bit cross-lane op processes BOTH
// samples -> per-sample cost halves on both the VALU and DS pipes (round-6
// profile: both pipes co-saturated at ~100 us each).
// f32 is kept for: init trig/fold (inputs), diag lane phases, epilogue
// probability reductions. f16 only for the gate chain (~40 ops deep;
// expected |dE| ~ 1e-2 < 2e-2 threshold).
// Round-12 = round-11 + compile fix: __builtin_amdgcn_cvt_pkrtz returns
// __fp16x2, bit_cast to h2 (_Float16x2).

namespace {

constexpr int NQB = 10;

typedef _Float16 h2 __attribute__((ext_vector_type(2)));
typedef unsigned int u32x2 __attribute__((ext_vector_type(2)));

__device__ __forceinline__ float h2_as_f(h2 v) { return __builtin_bit_cast(float, v); }
__device__ __forceinline__ h2 f_as_h2(float v) { return __builtin_bit_cast(h2, v); }

__device__ __forceinline__ h2 pk2(float a, float b) {
#if __has_builtin(__builtin_amdgcn_cvt_pkrtz)
  return __builtin_bit_cast(h2, __builtin_amdgcn_cvt_pkrtz(a, b));
#else
  h2 r; r.x = (_Float16)a; r.y = (_Float16)b; return r;
#endif
}

__device__ __forceinline__ h2 hsplat(float f) {
  const _Float16 h = (_Float16)f;
  h2 r; r.x = h; r.y = h; return r;
}

__device__ __forceinline__ h2 hsel(bool c, h2 a, h2 b) {
  return f_as_h2(c ? h2_as_f(a) : h2_as_f(b));
}

template<int CTRL>
__device__ __forceinline__ float dppf(float x) {
  return __uint_as_float((unsigned)__builtin_amdgcn_update_dpp(
      0, (int)__float_as_uint(x), CTRL, 0xF, 0xF, true));
}

// Partner value x[lane ^ (1<<P)] on a 32-bit container.
template<int P>
__device__ __forceinline__ float xorf(float x, int lane, int bpa) {
  if constexpr (P == 0) {
    return dppf<0xB1>(x);                       // quad_perm [1,0,3,2] = XOR1
  } else if constexpr (P == 1) {
    return dppf<0x4E>(x);                       // quad_perm [2,3,0,1] = XOR2
  } else if constexpr (P == 2) {
    return dppf<0x141>(dppf<0x1B>(x));          // XOR3 then XOR7 => XOR4
  } else if constexpr (P == 3) {
    return dppf<0x128>(x);                      // row_ror:8 == XOR8 within row16
  } else if constexpr (P == 4) {
#if __has_builtin(__builtin_amdgcn_permlane16_swap)
    u32x2 r = __builtin_amdgcn_permlane16_swap(__float_as_uint(x), __float_as_uint(x), false, false);
    // r.x[lane] = x[lane & ~16]; r.y[lane] = x[lane | 16]  (verified round 4)
    return __uint_as_float(((lane >> 4) & 1) ? r.x : r.y);
#else
    return __shfl_xor(x, 16, 64);
#endif
  } else {
    return __uint_as_float((unsigned)__builtin_amdgcn_ds_bpermute(
        bpa, (int)__float_as_uint(x)));         // bpa = (lane^32)<<2
  }
}

template<int P>
__device__ __forceinline__ h2 xorh(h2 v, int lane, int bpa) {
  return f_as_h2(xorf<P>(h2_as_f(v), lane, bpa));
}

__device__ __forceinline__ float fsin_rev(float rev) {
#if __has_builtin(__builtin_amdgcn_sinf)
  return __builtin_amdgcn_sinf(rev);
#else
  return __sinf(rev * 6.2831853071795864769f);
#endif
}
__device__ __forceinline__ float fcos_rev(float rev) {
#if __has_builtin(__builtin_amdgcn_cosf)
  return __builtin_amdgcn_cosf(rev);
#else
  return __cosf(rev * 6.2831853071795864769f);
#endif
}

__device__ __forceinline__ float clamp01(float x) {
#if __has_builtin(__builtin_amdgcn_fmed3f)
  return __builtin_amdgcn_fmed3f(x, 0.0f, 1.0f);
#else
  return fminf(fmaxf(x, 0.0f), 1.0f);
#endif
}

__device__ __forceinline__ void cmulf(float& r, float& i, float br, float bi) {
  const float tr = r * br - i * bi;
  i = r * bi + i * br;
  r = tr;
}

// ---- init: lane factor L = prod_{p=0..5} u_p[lane bit p] (f32, on-demand trig) ----
__device__ __forceinline__ void lane_fold(const float* __restrict__ xin, int lane,
                                          const float (*gm)[8], float& Lr, float& Li) {
  Lr = 1.0f; Li = 0.0f;
#pragma unroll
  for (int p = 0; p < 6; ++p) {
    const float r = 0.25f * clamp01(xin[9 - p]);
    const float fs = fsin_rev(r), fc = fcos_rev(r);
    const float* m = &gm[9 - p][0];
    const bool b = (lane >> p) & 1;
    const float m0 = b ? m[4] : m[0], m1 = b ? m[5] : m[1];
    const float m2 = b ? m[6] : m[2], m3 = b ? m[7] : m[3];
    const float ur = m0 * fc + m2 * fs;
    const float ui = m1 * fc + m3 * fs;
    if (p == 0) { Lr = ur; Li = ui; }
    else        cmulf(Lr, Li, ur, ui);
  }
}

// ---- init: one tree level (register bit). N existing nodes -> 2N. ----
template<int N>
__device__ __forceinline__ void tree_level(h2 (&Hr)[16], h2 (&Hi)[16],
                                           const float* m, float xa, float xb) {
  const float rA = 0.25f * clamp01(xa);
  const float sA = fsin_rev(rA), cA = fcos_rev(rA);
  const float rB = 0.25f * clamp01(xb);
  const float sB = fsin_rev(rB), cB = fcos_rev(rB);
  const h2 u0r = pk2(m[0]*cA + m[2]*sA, m[0]*cB + m[2]*sB);
  const h2 u0i = pk2(m[1]*cA + m[3]*sA, m[1]*cB + m[3]*sB);
  const h2 u1r = pk2(m[4]*cA + m[6]*sA, m[4]*cB + m[6]*sB);
  const h2 u1i = pk2(m[5]*cA + m[7]*sA, m[5]*cB + m[7]*sB);
#pragma unroll
  for (int k = 0; k < N; ++k) {
    const h2 ar = Hr[k], ai = Hi[k];
    Hr[k+N] = ar*u1r - ai*u1i;  Hi[k+N] = ar*u1i + ai*u1r;
    Hr[k]   = ar*u0r - ai*u0i;  Hi[k]   = ar*u0i + ai*u0r;
  }
}

// ---- diagonal: S[k] *= (zl) * (zk[k]) ----
__device__ __forceinline__ void apply_diag16(h2 (&Hr)[16], h2 (&Hi)[16],
                                             h2 zr, h2 zi, const h2 (*zk)[2]) {
#pragma unroll
  for (int k = 0; k < 16; ++k) {
    const h2 kc = zk[k][0], ks = zk[k][1];
    const h2 cr = zr*kc - zi*ks;
    const h2 ci = zi*kc + zr*ks;
    const h2 tr = cr*Hr[k] - ci*Hi[k];
    const h2 ti = ci*Hr[k] + cr*Hi[k];
    Hr[k] = tr;  Hi[k] = ti;
  }
}

// ---- real RY gates ----
template<int J>
__device__ __forceinline__ void ry_reg16(h2 (&Hr)[16], h2 (&Hi)[16], h2 c, h2 s) {
#pragma unroll
  for (int k0 = 0; k0 < 16; ++k0) {
    if (k0 & J) continue;
    const int k1 = k0 | J;
    const h2 a0r = Hr[k0], a1r = Hr[k1], a0i = Hi[k0], a1i = Hi[k1];
    Hr[k0] = c*a0r - s*a1r;  Hr[k1] = s*a0r + c*a1r;
    Hi[k0] = c*a0i - s*a1i;  Hi[k1] = s*a0i + c*a1i;
  }
}

template<int P>
__device__ __forceinline__ void ry_lane16(h2 (&Hr)[16], h2 (&Hi)[16], h2 c, h2 ss,
                                          int lane, int bpa) {
#pragma unroll
  for (int k = 0; k < 16; ++k) {
    const h2 pr = xorh<P>(Hr[k], lane, bpa);
    const h2 pi = xorh<P>(Hi[k], lane, bpa);
    Hr[k] = c*Hr[k] + ss*pr;
    Hi[k] = c*Hi[k] + ss*pi;
  }
}

// ---- CRY gates ----
template<int CB, int J>
__device__ __forceinline__ void cry_rr(h2 (&Hr)[16], h2 (&Hi)[16], h2 c, h2 s) {
#pragma unroll
  for (int k0 = 0; k0 < 16; ++k0) {
    if ((k0 & J) || !(k0 & CB)) continue;
    const int k1 = k0 | J;
    const h2 a0r = Hr[k0], a1r = Hr[k1], a0i = Hi[k0], a1i = Hi[k1];
    Hr[k0] = c*a0r - s*a1r;  Hr[k1] = s*a0r + c*a1r;
    Hi[k0] = c*a0i - s*a1i;  Hi[k1] = s*a0i + c*a1i;
  }
}

// ctrl = k bit0 (amp bit6), target lane bit 5
__device__ __forceinline__ void cry_k0_l5(h2 (&Hr)[16], h2 (&Hi)[16], h2 c, h2 s,
                                          int lane, int bpa) {
  const h2 ss = hsel((lane >> 5) & 1, s, -s);
#pragma unroll
  for (int k = 1; k < 16; k += 2) {
    const h2 pr = xorh<5>(Hr[k], lane, bpa);
    const h2 pi = xorh<5>(Hi[k], lane, bpa);
    Hr[k] = c*Hr[k] + ss*pr;
    Hi[k] = c*Hi[k] + ss*pi;
  }
}

template<int PC, int PT>
__device__ __forceinline__ void cry_ll(h2 (&Hr)[16], h2 (&Hi)[16], h2 c, h2 s,
                                       h2 HONE, h2 HZERO, int lane, int bpa) {
  const bool ctrl = (lane >> PC) & 1;
  const h2 ce = hsel(ctrl, c, HONE);
  const h2 se = hsel(ctrl, s, HZERO);
  const h2 ss = hsel((lane >> PT) & 1, se, -se);
#pragma unroll
  for (int k = 0; k < 16; ++k) {
    const h2 pr = xorh<PT>(Hr[k], lane, bpa);
    const h2 pi = xorh<PT>(Hi[k], lane, bpa);
    Hr[k] = ce*Hr[k] + ss*pr;
    Hi[k] = ce*Hi[k] + ss*pi;
  }
}

// ctrl = lane bit 0, target reg bit 3 (amp bit 9)
__device__ __forceinline__ void cry_l0_r8(h2 (&Hr)[16], h2 (&Hi)[16], h2 c, h2 s,
                                          h2 HONE, h2 HZERO, int lane) {
  const bool ctrl = lane & 1;
  const h2 ce = hsel(ctrl, c, HONE);
  const h2 se = hsel(ctrl, s, HZERO);
#pragma unroll
  for (int k0 = 0; k0 < 8; ++k0) {
    const int k1 = k0 + 8;
    const h2 a0r = Hr[k0], a1r = Hr[k1], a0i = Hi[k0], a1i = Hi[k1];
    Hr[k0] = ce*a0r - se*a1r;  Hr[k1] = se*a0r + ce*a1r;
    Hi[k0] = ce*a0i - se*a1i;  Hi[k1] = se*a0i + ce*a1i;
  }
}

// ---- epilogue per sample: 16 probs -> 10 expvals, write ----
__device__ __forceinline__ void finish_sample(const float (&p)[16], int lane, int bpa,
                                              float* __restrict__ outp) {
  // register-bit contractions (k bit0..3 = amp bits 6..9; sign + when bit==0)
  float t[8], T[4];
  float e6 = 0.0f;
#pragma unroll
  for (int j = 0; j < 8; ++j) { t[j] = p[2*j] + p[2*j+1]; e6 += p[2*j] - p[2*j+1]; }
  float e7 = 0.0f;
#pragma unroll
  for (int j = 0; j < 4; ++j) { T[j] = t[2*j] + t[2*j+1]; e7 += t[2*j] - t[2*j+1]; }
  const float U0 = T[0] + T[1], U1 = T[2] + T[3];
  const float e8 = (T[0] - T[1]) + (T[2] - T[3]);
  const float tot = U0 + U1;
  const float e9 = U0 - U1;

  float sgn[6];
#pragma unroll
  for (int q = 0; q < 6; ++q) sgn[q] = ((lane >> q) & 1) ? -1.0f : 1.0f;

  float E[6];
  float tt = tot;
#define QSTEP(P)                                                   \
  {                                                                \
    const float pt = xorf<P>(tt, lane, bpa);                       \
    E[P] = sgn[P] * (tt - pt);                                     \
    tt += pt;                                                      \
    _Pragma("unroll")                                              \
    for (int jj = 0; jj < P; ++jj) E[jj] += xorf<P>(E[jj], lane, bpa); \
  }
  QSTEP(0) QSTEP(1) QSTEP(2) QSTEP(3) QSTEP(4) QSTEP(5)
#undef QSTEP

  float a6 = e6, a7 = e7, a8 = e8, a9 = e9;
#define RSTEP(P)                       \
  a6 += xorf<P>(a6, lane, bpa);        \
  a7 += xorf<P>(a7, lane, bpa);        \
  a8 += xorf<P>(a8, lane, bpa);        \
  a9 += xorf<P>(a9, lane, bpa);
  RSTEP(0) RSTEP(1) RSTEP(2) RSTEP(3) RSTEP(4) RSTEP(5)
#undef RSTEP

  // out[q], q = 9 - p: q=0..3 <- bits 9,8,7,6 ; q=4..9 <- E[5..0]
  if (lane < 10) {
    float v = a9;
    v = (lane == 1) ? a8 : v;
    v = (lane == 2) ? a7 : v;
    v = (lane == 3) ? a6 : v;
    v = (lane == 4) ? E[5] : v;
    v = (lane == 5) ? E[4] : v;
    v = (lane == 6) ? E[3] : v;
    v = (lane == 7) ? E[2] : v;
    v = (lane == 8) ? E[1] : v;
    v = (lane == 9) ? E[0] : v;
    outp[lane] = v;
  }
}

} // namespace

__global__ __launch_bounds__(256)
void qlayer_kernel(const float* __restrict__ inp,   // (B, 10)
                   const float* __restrict__ wt,    // (80,)
                   float* __restrict__ out,         // (B, 10)
                   int B)
{
  __shared__ float gm[10][8];        // layer-0 Rot matrices (f32)
  __shared__ h2 gch[20][2];          // CRY {c,s} splats, both layers
  __shared__ h2 grot1h[10][2];       // layer-1 RY {c,s} splats
  __shared__ h2 gdk[2][16][2];       // layer-1 diag reg phases {c,s} splats
  __shared__ float gzlane[2][64][2]; // per-lane diag phase (c,s): [0]=phi,[1]=omega

  const int tid = threadIdx.x;

  // ---- setup (disjoint thread ranges) ----
  if (tid < 10) {
    // layer-0 Rot(phi, theta, omega) = RZ(omega) RY(theta) RZ(phi)
    const int w = 3 * tid;
    const float phi = wt[w], th = wt[w + 1], om = wt[w + 2];
    float s, c, sa, ca, sb, cb;
    __sincosf(0.5f * th, &s, &c);
    __sincosf(0.5f * (phi + om), &sa, &ca);
    __sincosf(0.5f * (phi - om), &sb, &cb);
    gm[tid][0] =  c * ca;  gm[tid][1] = -c * sa;   // u00
    gm[tid][2] = -s * cb;  gm[tid][3] = -s * sb;   // u01
    gm[tid][4] =  s * cb;  gm[tid][5] = -s * sb;   // u10
    gm[tid][6] =  c * ca;  gm[tid][7] =  c * sa;   // u11
  } else if (tid >= 16 && tid < 36) {
    const int g = tid - 16;
    const int layer = g / 10, e = g - 10 * layer;
    const int w = layer * 40 + 30 + e;
    float s, c;
    __sincosf(0.5f * wt[w], &s, &c);
    gch[g][0] = hsplat(c);
    gch[g][1] = hsplat(s);
  } else if (tid >= 48 && tid < 58) {
    const int q = tid - 48;
    float s, c;
    __sincosf(0.5f * wt[41 + 3 * q], &s, &c);    // layer-1 theta_q
    grot1h[q][0] = hsplat(c);
    grot1h[q][1] = hsplat(s);
  } else if (tid >= 64 && tid < 96) {
    // diag reg tables: k bit0<->q3(+9), bit1<->q2(+6), bit2<->q1(+3), bit3<->q0(+0)
    const int t = tid - 64;
    const int d = t >> 4, k = t & 15;
    const int wb = d ? 42 : 40;
    float ang = 0.0f;
    if (k & 1) ang += wt[wb + 9];
    if (k & 2) ang += wt[wb + 6];
    if (k & 4) ang += wt[wb + 3];
    if (k & 8) ang += wt[wb + 0];
    float s, c;
    __sincosf(ang, &s, &c);
    gdk[d][k][0] = hsplat(c);
    gdk[d][k][1] = hsplat(s);
  } else if (tid >= 128) {
    // per-lane diag phase (lane bit p <-> qubit 9-p)
    const int d = (tid - 128) >> 6, ln = tid & 63;
    const int wb = d ? 42 : 40;
    float ang = 0.0f;
    if (ln & 1)  ang += wt[wb + 27];
    if (ln & 2)  ang += wt[wb + 24];
    if (ln & 4)  ang += wt[wb + 21];
    if (ln & 8)  ang += wt[wb + 18];
    if (ln & 16) ang += wt[wb + 15];
    if (ln & 32) ang += wt[wb + 12];
    float s, c;
    __sincosf(ang, &s, &c);
    gzlane[d][ln][0] = c;
    gzlane[d][ln][1] = s;
  }
  __syncthreads();

  const int lane = tid & 63;
  const int bpa = (lane ^ 32) << 2;
  const int half = B >> 1;
  const int gw = blockIdx.x * 4 + (tid >> 6);
  if (gw >= half) return;
  const int sA = gw, sB = gw + half;
  const float* xA = inp + sA * NQB;
  const float* xB = inp + sB * NQB;

  const h2 HONE  = hsplat(1.0f);
  const h2 HZERO = hsplat(0.0f);

  // ---- init: (embedding RY + layer-0 Rot) product state, packed {A,B} ----
  float LrA, LiA, LrB, LiB;
  lane_fold(xA, lane, gm, LrA, LiA);
  lane_fold(xB, lane, gm, LrB, LiB);

  h2 Hr[16], Hi[16];
  Hr[0] = pk2(LrA, LrB);
  Hi[0] = pk2(LiA, LiB);
  tree_level<1>(Hr, Hi, &gm[3][0], xA[3], xB[3]);   // amp bit 6 (q=3)
  tree_level<2>(Hr, Hi, &gm[2][0], xA[2], xB[2]);   // amp bit 7 (q=2)
  tree_level<4>(Hr, Hi, &gm[1][0], xA[1], xB[1]);   // amp bit 8 (q=1)
  tree_level<8>(Hr, Hi, &gm[0][0], xA[0], xB[0]);   // amp bit 9 (q=0)

  // ---- layer 0: CRY ring (Rot folded into init) ----
  {
    const h2 (*cc)[2] = &gch[0];
    cry_rr<8, 4>(Hr, Hi, cc[0][0], cc[0][1]);                 // (q0,q1): p9->p8
    cry_rr<4, 2>(Hr, Hi, cc[1][0], cc[1][1]);                 // (q1,q2)
    cry_rr<2, 1>(Hr, Hi, cc[2][0], cc[2][1]);                 // (q2,q3)
    cry_k0_l5   (Hr, Hi, cc[3][0], cc[3][1], lane, bpa);      // (q3,q4): k0 ctrl, lane5 tgt
    cry_ll<5, 4>(Hr, Hi, cc[4][0], cc[4][1], HONE, HZERO, lane, bpa);
    cry_ll<4, 3>(Hr, Hi, cc[5][0], cc[5][1], HONE, HZERO, lane, bpa);
    cry_ll<3, 2>(Hr, Hi, cc[6][0], cc[6][1], HONE, HZERO, lane, bpa);
    cry_ll<2, 1>(Hr, Hi, cc[7][0], cc[7][1], HONE, HZERO, lane, bpa);
    cry_ll<1, 0>(Hr, Hi, cc[8][0], cc[8][1], HONE, HZERO, lane, bpa);
    cry_l0_r8   (Hr, Hi, cc[9][0], cc[9][1], HONE, HZERO, lane);  // (q9,q0)
  }

  // ---- layer 1: D_phi -> real RY layer -> D_omega -> CRY ring ----
  {
    const float2 zp = *(const float2*)&gzlane[0][lane][0];
    apply_diag16(Hr, Hi, hsplat(zp.x), hsplat(zp.y), &gdk[0][0]);
    ry_reg16<8>(Hr, Hi, grot1h[0][0], grot1h[0][1]);          // q=0, k3
    ry_reg16<4>(Hr, Hi, grot1h[1][0], grot1h[1][1]);          // q=1, k2
    ry_reg16<2>(Hr, Hi, grot1h[2][0], grot1h[2][1]);          // q=2, k1
    ry_reg16<1>(Hr, Hi, grot1h[3][0], grot1h[3][1]);          // q=3, k0
    {
      const h2 s5 = grot1h[4][1];
      ry_lane16<5>(Hr, Hi, grot1h[4][0], hsel((lane >> 5) & 1, s5, -s5), lane, bpa);
      const h2 s4 = grot1h[5][1];
      ry_lane16<4>(Hr, Hi, grot1h[5][0], hsel((lane >> 4) & 1, s4, -s4), lane, bpa);
      const h2 s3 = grot1h[6][1];
      ry_lane16<3>(Hr, Hi, grot1h[6][0], hsel((lane >> 3) & 1, s3, -s3), lane, bpa);
      const h2 s2 = grot1h[7][1];
      ry_lane16<2>(Hr, Hi, grot1h[7][0], hsel((lane >> 2) & 1, s2, -s2), lane, bpa);
      const h2 s1 = grot1h[8][1];
      ry_lane16<1>(Hr, Hi, grot1h[8][0], hsel((lane >> 1) & 1, s1, -s1), lane, bpa);
      const h2 s0 = grot1h[9][1];
      ry_lane16<0>(Hr, Hi, grot1h[9][0], hsel(lane & 1, s0, -s0), lane, bpa);
    }
    const float2 zo = *(const float2*)&gzlane[1][lane][0];
    apply_diag16(Hr, Hi, hsplat(zo.x), hsplat(zo.y), &gdk[1][0]);

    const h2 (*cc)[2] = &gch[10];
    cry_rr<8, 4>(Hr, Hi, cc[0][0], cc[0][1]);
    cry_rr<4, 2>(Hr, Hi, cc[1][0], cc[1][1]);
    cry_rr<2, 1>(Hr, Hi, cc[2][0], cc[2][1]);
    cry_k0_l5   (Hr, Hi, cc[3][0], cc[3][1], lane, bpa);
    cry_ll<5, 4>(Hr, Hi, cc[4][0], cc[4][1], HONE, HZERO, lane, bpa);
    cry_ll<4, 3>(Hr, Hi, cc[5][0], cc[5][1], HONE, HZERO, lane, bpa);
    cry_ll<3, 2>(Hr, Hi, cc[6][0], cc[6][1], HONE, HZERO, lane, bpa);
    cry_ll<2, 1>(Hr, Hi, cc[7][0], cc[7][1], HONE, HZERO, lane, bpa);
    cry_ll<1, 0>(Hr, Hi, cc[8][0], cc[8][1], HONE, HZERO, lane, bpa);
    cry_l0_r8   (Hr, Hi, cc[9][0], cc[9][1], HONE, HZERO, lane);
  }

  // ---- probabilities (f32) and per-sample expvals ----
  float pA[16], pB[16];
#pragma unroll
  for (int k = 0; k < 16; ++k) {
    const float rA = (float)Hr[k].x, rB = (float)Hr[k].y;
    const float iA = (float)Hi[k].x, iB = (float)Hi[k].y;
    pA[k] = rA * rA + iA * iA;
    pB[k] = rB * rB + iB * iB;
  }
  finish_sample(pA, lane, bpa, out + sA * NQB);
  finish_sample(pB, lane, bpa, out + sB * NQB);
}

extern "C" void kernel_launch(void* const* d_in, const int* in_sizes, int n_in,
                              void* d_out, int out_size, void* d_ws, size_t ws_size,
                              hipStream_t stream) {
  const float* inp = (const float*)d_in[0];
  const float* wt  = (const float*)d_in[1];
  float* out = (float*)d_out;
  const int B = in_sizes[0] / NQB;              // 32768
  const int pairs = B / 2;                      // 16384 waves
  const int nblocks = (pairs + 3) / 4;          // 4096
  hipLaunchKernelGGL(qlayer_kernel, dim3(nblocks), dim3(256), 0, stream,
                     inp, wt, out, B);
}